// Round 11
// baseline (162.498 us; speedup 1.0000x reference)
//
#include <hip/hip_runtime.h>
#include <math.h>

// DMP rollout: DIM=1024, NB=25, T=10001 rows of [y0 | y | dy] (3*1024 fp32).
// v=(y,dy) affine recurrence, constant 2x2 A; u_t=(dt^2,dt)*e_t,
// e_t = 156.25*g + (w.q_t)*(g-y0); q_t closed-form. 5 kernels:
//  k_prep  : q rows + per-chunk coef vectors QY/QD (f64) + W transpose.
//  k_dots  : per (c,d) chunk offset (coalesced WT).      [dots in d_out scratch]
//  k_scanA : level-1 zero-init partials per superchunk (f64).
//  k_scanBC: level-2 prefix (recomputed per block) + recover chunk starts (f64).
//  k_roll  : 1 block = 1 chunk; replay 20 fp32 steps; assemble full rows in
//            LDS ping-pong; stream each chunk as ONE contiguous 240KB span of
//            float4 stores (fill-kernel-like pattern) -> test store-layout theory.

#define DIM    1024
#define NB     25
#define NSTEP  10000
#define CHUNKS 500
#define LSTEPS 20
#define SC     25     // superchunks
#define SS     20     // chunks per superchunk
#define QS     32     // padded q row stride (floats)

__global__ __launch_bounds__(64) void k_prep(float* __restrict__ q,
                                             float* __restrict__ QY,
                                             float* __restrict__ QD,
                                             float* __restrict__ WT,
                                             const float* __restrict__ W,
                                             double logdecay,
                                             double a00, double a01,
                                             double a10, double a11) {
    const int c = blockIdx.x;
    const int tid = threadIdx.x;
    if (c >= CHUNKS) {                       // W transpose blocks
        int k = c - CHUNKS;                  // 0..24
        for (int d = tid; d < DIM; d += 64)
            WT[k * DIM + d] = W[d * NB + k];
        return;
    }
    __shared__ float lq[LSTEPS][NB + 1];
    if (tid < LSTEPS) {
        int t = c * LSTEPS + tid + 1;        // x after decay at step t
        float x = (float)exp((double)t * logdecay);
        float psi[NB];
        float S = 0.f;
#pragma unroll
        for (int k = 0; k < NB; ++k) {
            float lk = (10.0f / 24.0f) * (float)k;   // linspace(0,10,25)
            float ck = expf(-lk);
            float hk = 25.0f / ck;
            float dxc = x - ck;
            float p = expf(-hk * dxc * dxc);
            psi[k] = p;
            S += p;
        }
        float scale = 1000.0f * x / S;
        float* qrow = q + (size_t)(c * LSTEPS + tid) * QS;
#pragma unroll
        for (int k = 0; k < NB; ++k) {
            float v = psi[k] * scale;
            qrow[k] = v;
            lq[tid][k] = v;
        }
#pragma unroll
        for (int k = NB; k < QS; ++k) qrow[k] = 0.f;
    }
    __syncthreads();
    if (tid < NB) {
        // p_j = A^(L-1-j) (dt^2, dt)^T accumulated backward in f64
        double py = (double)0.001f * (double)0.001f;
        double pd = (double)0.001f;
        double qy = 0.0, qd = 0.0;
        for (int j = LSTEPS - 1; j >= 0; --j) {
            double v = (double)lq[j][tid];
            qy += py * v;
            qd += pd * v;
            double npy = a00 * py + a01 * pd;
            double npd = a10 * py + a11 * pd;
            py = npy; pd = npd;
        }
        QY[c * QS + tid] = (float)qy;
        QD[c * QS + tid] = (float)qd;
    }
}

__global__ __launch_bounds__(256) void k_dots(const float* __restrict__ QY,
                                              const float* __restrict__ QD,
                                              const float* __restrict__ WT,
                                              const float* __restrict__ g,
                                              const float* __restrict__ y0,
                                              float* __restrict__ dots,
                                              double spY, double spD) {
    const int idx = blockIdx.x * 256 + threadIdx.x;   // DIM*CHUNKS threads
    const int d = idx & (DIM - 1);
    const int c = idx >> 10;                          // block-uniform
    const float gd  = g[d];
    const float gd0 = gd - y0[d];
    float sy = 0.f, sd = 0.f;
#pragma unroll
    for (int k = 0; k < NB; ++k) {
        float wk = WT[k * DIM + d];          // coalesced
        sy += wk * QY[c * QS + k];           // uniform
        sd += wk * QD[c * QS + k];
    }
    dots[c * DIM + d]                = (float)((double)gd * spY + (double)gd0 * (double)sy);
    dots[CHUNKS * DIM + c * DIM + d] = (float)((double)gd * spD + (double)gd0 * (double)sd);
}

// level-1: per (superchunk, dim) zero-init partial over its SS chunks
__global__ __launch_bounds__(256) void k_scanA(const float* __restrict__ dots,
                                               float* __restrict__ usY,
                                               float* __restrict__ usD,
                                               double m00, double m01,
                                               double m10, double m11) {
    const int idx = blockIdx.x * 256 + threadIdx.x;   // DIM*SC threads
    const int d = idx & (DIM - 1);
    const int s = idx >> 10;
    double vy = 0.0, vdy = 0.0;
#pragma unroll 4
    for (int i = 0; i < SS; ++i) {
        int c = s * SS + i;
        double ry = (double)dots[c * DIM + d];
        double rd = (double)dots[CHUNKS * DIM + c * DIM + d];
        double ny  = m00 * vy + m01 * vdy + ry;
        double ndy = m10 * vy + m11 * vdy + rd;
        vy = ny; vdy = ndy;
    }
    usY[s * DIM + d] = (float)vy;
    usD[s * DIM + d] = (float)vdy;
}

// level-2 prefix (recomputed per block, trivial) + level-3 chunk-start recovery
__global__ __launch_bounds__(256) void k_scanBC(const float* __restrict__ dots,
                                                const float* __restrict__ usY,
                                                const float* __restrict__ usD,
                                                const float* __restrict__ y0,
                                                float* __restrict__ vs,
                                                double m00, double m01,
                                                double m10, double m11,
                                                double b00, double b01,
                                                double b10, double b11) {
    const int b = blockIdx.x;                 // 100 blocks = SC * 4
    const int s = b >> 2;
    const int d = (b & 3) * 256 + threadIdx.x;
    double vy = (double)y0[d], vdy = 0.0;
    for (int i = 0; i < s; ++i) {             // superchunk prefix with B = M^SS
        double uy = (double)usY[i * DIM + d];
        double ud = (double)usD[i * DIM + d];
        double ny  = b00 * vy + b01 * vdy + uy;
        double ndy = b10 * vy + b11 * vdy + ud;
        vy = ny; vdy = ndy;
    }
#pragma unroll 4
    for (int i = 0; i < SS; ++i) {            // recover chunk starts with M
        int c = s * SS + i;
        vs[c * DIM + d] = (float)vy;
        vs[CHUNKS * DIM + c * DIM + d] = (float)vdy;
        double ry = (double)dots[c * DIM + d];
        double rd = (double)dots[CHUNKS * DIM + c * DIM + d];
        double ny  = m00 * vy + m01 * vdy + ry;
        double ndy = m10 * vy + m11 * vdy + rd;
        vy = ny; vdy = ndy;
    }
}

// 1 block = 1 chunk. 512 threads, 2 dims each. Row assembled in LDS, then
// streamed as contiguous float4s (fill-like linear store pattern).
__global__ __launch_bounds__(512) void k_roll(const float* __restrict__ q,
                                              const float* __restrict__ WT,
                                              const float* __restrict__ g,
                                              const float* __restrict__ y0,
                                              const float* __restrict__ vs,
                                              float* __restrict__ out) {
    __shared__ float lq[LSTEPS][QS];          // 2.56 KB
    __shared__ float rowY[2][DIM];            // 8 KB ping-pong
    __shared__ float rowD[2][DIM];            // 8 KB ping-pong
    const int c = blockIdx.x;
    const int tid = threadIdx.x;
    const int d0 = tid;
    const int d1 = tid + 512;
    if (tid < LSTEPS * QS / 4)
        ((float4*)&lq[0][0])[tid] = ((const float4*)(q + (size_t)c * LSTEPS * QS))[tid];

    float w0[NB], w1[NB];
#pragma unroll
    for (int k = 0; k < NB; ++k) {
        w0[k] = WT[k * DIM + d0];             // coalesced
        w1[k] = WT[k * DIM + d1];
    }
    const float g0 = g[d0], g1 = g[d1];
    const float gd00 = g0 - y0[d0], gd01 = g1 - y0[d1];
    float y_0  = vs[c * DIM + d0];
    float y_1  = vs[c * DIM + d1];
    float dy_0 = vs[CHUNKS * DIM + c * DIM + d0];
    float dy_1 = vs[CHUNKS * DIM + c * DIM + d1];
    // constant y0 float4 for the y0-section of every row (tid<256 only)
    float4 y0q = make_float4(0.f, 0.f, 0.f, 0.f);
    if (tid < 256) y0q = ((const float4*)y0)[tid];

    if (c == 0) {                             // row 0: [y0 | y0 | 0]
        float4* o = (float4*)out;
        if (tid < 256) {
            o[tid]       = y0q;
            o[256 + tid] = y0q;
            o[512 + tid] = make_float4(0.f, 0.f, 0.f, 0.f);
        }
    }
    __syncthreads();                          // lq staged

    float* base = out + (size_t)(c * LSTEPS + 1) * (3 * DIM);
    for (int j = 0; j < LSTEPS; ++j) {
        const float4* row = (const float4*)&lq[j][0];   // broadcast reads
        float dot0 = 0.f, dot1 = 0.f;
#pragma unroll
        for (int m = 0; m < 6; ++m) {
            float4 qv = row[m];
            dot0 += w0[4 * m + 0] * qv.x; dot1 += w1[4 * m + 0] * qv.x;
            dot0 += w0[4 * m + 1] * qv.y; dot1 += w1[4 * m + 1] * qv.y;
            dot0 += w0[4 * m + 2] * qv.z; dot1 += w1[4 * m + 2] * qv.z;
            dot0 += w0[4 * m + 3] * qv.w; dot1 += w1[4 * m + 3] * qv.w;
        }
        float q24 = lq[j][24];
        dot0 += w0[24] * q24;
        dot1 += w1[24] * q24;
        float f0 = dot0 * gd00, f1 = dot1 * gd01;
        float ddy0 = 25.0f * (6.25f * (g0 - y_0) - dy_0) + f0;
        float ddy1 = 25.0f * (6.25f * (g1 - y_1) - dy_1) + f1;
        dy_0 = dy_0 + 0.001f * ddy0;
        dy_1 = dy_1 + 0.001f * ddy1;
        y_0  = y_0 + 0.001f * dy_0;
        y_1  = y_1 + 0.001f * dy_1;
        const int pb = j & 1;
        rowY[pb][d0] = y_0;  rowY[pb][d1] = y_1;
        rowD[pb][d0] = dy_0; rowD[pb][d1] = dy_1;
        __syncthreads();
        float4* op = (float4*)(base + (size_t)j * (3 * DIM));   // 768 float4s
        if (tid < 256) {
            op[tid]       = y0q;                                 // y0 section
            op[512 + tid] = *(const float4*)&rowD[pb][tid * 4];  // dy section
        } else {
            op[tid]       = *(const float4*)&rowY[pb][(tid - 256) * 4]; // y section
        }
    }
}

extern "C" void kernel_launch(void* const* d_in, const int* in_sizes, int n_in,
                              void* d_out, int out_size, void* d_ws, size_t ws_size,
                              hipStream_t stream) {
    const float* y0 = (const float*)d_in[0];
    const float* g  = (const float*)d_in[1];
    const float* W  = (const float*)d_in[2];
    float* out = (float*)d_out;

    float* q   = (float*)d_ws;                        // [NSTEP][QS]      1.28 MB
    float* QY  = q   + (size_t)NSTEP * QS;            // [CHUNKS][QS]     64 KB
    float* QD  = QY  + (size_t)CHUNKS * QS;           //                  64 KB
    float* WT  = QD  + (size_t)CHUNKS * QS;           // [NB][DIM]        100 KB
    float* usY = WT  + (size_t)NB * DIM;              // [SC][DIM]        100 KB
    float* usD = usY + (size_t)SC * DIM;              //                  100 KB
    float* vs  = usD + (size_t)SC * DIM;              // [2][CHUNKS][DIM] 4 MB
    float* dots = out;                                // scratch in d_out (pre-roll)

    // A (f64 with fp32-rounded dt), M = A^L, B = M^SS, sp = 156.25*sum A^i(dt^2,dt)
    const double dtD = (double)0.001f;
    const double aD = 25.0, abD = 25.0 * 6.25;
    const double a00 = 1.0 - dtD * dtD * abD;
    const double a01 = dtD * (1.0 - dtD * aD);
    const double a10 = -dtD * abD;
    const double a11 = 1.0 - dtD * aD;
    double m00 = 1, m01 = 0, m10 = 0, m11 = 1;
    double py = dtD * dtD, pd = dtD, sY = 0.0, sD = 0.0;
    for (int i = 0; i < LSTEPS; ++i) {
        double t00 = a00 * m00 + a01 * m10;
        double t01 = a00 * m01 + a01 * m11;
        double t10 = a10 * m00 + a11 * m10;
        double t11 = a10 * m01 + a11 * m11;
        m00 = t00; m01 = t01; m10 = t10; m11 = t11;
        sY += py; sD += pd;
        double npy = a00 * py + a01 * pd;
        double npd = a10 * py + a11 * pd;
        py = npy; pd = npd;
    }
    double b00 = 1, b01 = 0, b10 = 0, b11 = 1;        // B = M^SS
    for (int i = 0; i < SS; ++i) {
        double t00 = m00 * b00 + m01 * b10;
        double t01 = m00 * b01 + m01 * b11;
        double t10 = m10 * b00 + m11 * b10;
        double t11 = m10 * b01 + m11 * b11;
        b00 = t00; b01 = t01; b10 = t10; b11 = t11;
    }
    const double spY = 156.25 * sY;
    const double spD = 156.25 * sD;
    const double logdecay = log((double)(1.0f - 0.001f));

    k_prep<<<CHUNKS + NB, 64, 0, stream>>>(q, QY, QD, WT, W, logdecay, a00, a01, a10, a11);
    k_dots<<<(DIM * CHUNKS) / 256, 256, 0, stream>>>(QY, QD, WT, g, y0, dots, spY, spD);
    k_scanA<<<(DIM * SC) / 256, 256, 0, stream>>>(dots, usY, usD, m00, m01, m10, m11);
    k_scanBC<<<SC * 4, 256, 0, stream>>>(dots, usY, usD, y0, vs, m00, m01, m10, m11,
                                         b00, b01, b10, b11);
    k_roll<<<CHUNKS, 512, 0, stream>>>(q, WT, g, y0, vs, out);
}

// Round 12
// 160.338 us; speedup vs baseline: 1.0135x; 1.0135x over previous
//
#include <hip/hip_runtime.h>
#include <math.h>

// DMP rollout: DIM=1024, NB=25, T=10001 rows of [y0 | y | dy] (3*1024 fp32).
// v=(y,dy) affine recurrence, constant 2x2 A; u_t=(dt^2,dt)*e_t,
// e_t = 156.25*g + (w.q_t)*(g-y0); q_t closed-form.
// 4 kernels (R10's 6 fused to cut dispatch gaps; roll reverted to R10-best):
//  k_prep : q rows + per-chunk coef vectors QY/QD (f64 backward) + W transpose.
//  k_midA : per (superchunk s, dim d): dots computed on the fly + f64 partial
//           over SS chunks -> usY/usD.           (was k_dots + k_scanA)
//  k_midB : per (s,d): superchunk prefix (recompute) + recover SS chunk start
//           states -> vs, dots recomputed on the fly.  (was k_scanB + k_scanC)
//  k_roll : R10 structure verbatim: grid (4,250)x256, per-thread 40 fp32 steps,
//           q slice in LDS (broadcast b128), 3 coalesced dword store streams.

#define DIM    1024
#define NB     25
#define NSTEP  10000
#define CHUNKS 250
#define LSTEPS 40
#define SC     25     // superchunks
#define SS     10     // chunks per superchunk
#define QS     32     // padded q row stride (floats)

__global__ __launch_bounds__(64) void k_prep(float* __restrict__ q,
                                             float* __restrict__ QY,
                                             float* __restrict__ QD,
                                             float* __restrict__ WT,
                                             const float* __restrict__ W,
                                             double logdecay,
                                             double a00, double a01,
                                             double a10, double a11) {
    const int c = blockIdx.x;
    const int tid = threadIdx.x;
    if (c >= CHUNKS) {                       // W transpose blocks
        int k = c - CHUNKS;                  // 0..24
        for (int d = tid; d < DIM; d += 64)
            WT[k * DIM + d] = W[d * NB + k];
        return;
    }
    __shared__ float lq[LSTEPS][NB + 1];
    if (tid < LSTEPS) {
        int t = c * LSTEPS + tid + 1;        // x after decay at step t
        float x = (float)exp((double)t * logdecay);
        float psi[NB];
        float S = 0.f;
#pragma unroll
        for (int k = 0; k < NB; ++k) {
            float lk = (10.0f / 24.0f) * (float)k;   // linspace(0,10,25)
            float ck = expf(-lk);
            float hk = 25.0f / ck;
            float dxc = x - ck;
            float p = expf(-hk * dxc * dxc);
            psi[k] = p;
            S += p;
        }
        float scale = 1000.0f * x / S;
        float* qrow = q + (size_t)(c * LSTEPS + tid) * QS;
#pragma unroll
        for (int k = 0; k < NB; ++k) {
            float v = psi[k] * scale;
            qrow[k] = v;
            lq[tid][k] = v;
        }
    }
    __syncthreads();
    if (tid < NB) {
        // p_j = A^(L-1-j) (dt^2, dt)^T accumulated backward in f64
        double py = (double)0.001f * (double)0.001f;
        double pd = (double)0.001f;
        double qy = 0.0, qd = 0.0;
        for (int j = LSTEPS - 1; j >= 0; --j) {
            double v = (double)lq[j][tid];
            qy += py * v;
            qd += pd * v;
            double npy = a00 * py + a01 * pd;
            double npd = a10 * py + a11 * pd;
            py = npy; pd = npd;
        }
        QY[c * QS + tid] = (float)qy;
        QD[c * QS + tid] = (float)qd;
    }
}

// per (superchunk, dim): chunk offsets on the fly + zero-init f64 partial
__global__ __launch_bounds__(256) void k_midA(const float* __restrict__ QY,
                                              const float* __restrict__ QD,
                                              const float* __restrict__ WT,
                                              const float* __restrict__ g,
                                              const float* __restrict__ y0,
                                              float* __restrict__ usY,
                                              float* __restrict__ usD,
                                              double spY, double spD,
                                              double m00, double m01,
                                              double m10, double m11) {
    const int b = blockIdx.x;                 // 100 = SC*4
    const int s = b >> 2;
    const int d = (b & 3) * 256 + threadIdx.x;
    float w[NB];
#pragma unroll
    for (int k = 0; k < NB; ++k) w[k] = WT[k * DIM + d];   // coalesced
    const float gd  = g[d];
    const float gd0 = gd - y0[d];
    double vy = 0.0, vdy = 0.0;
    for (int i = 0; i < SS; ++i) {
        int c = s * SS + i;
        float sy = 0.f, sd = 0.f;
#pragma unroll
        for (int k = 0; k < NB; ++k) {
            sy += w[k] * QY[c * QS + k];      // uniform -> scalar loads
            sd += w[k] * QD[c * QS + k];
        }
        double ry = (double)(float)((double)gd * spY + (double)gd0 * (double)sy);
        double rd = (double)(float)((double)gd * spD + (double)gd0 * (double)sd);
        double ny  = m00 * vy + m01 * vdy + ry;
        double ndy = m10 * vy + m11 * vdy + rd;
        vy = ny; vdy = ndy;
    }
    usY[s * DIM + d] = (float)vy;
    usD[s * DIM + d] = (float)vdy;
}

// per (superchunk, dim): prefix over earlier superchunks + recover chunk starts
__global__ __launch_bounds__(256) void k_midB(const float* __restrict__ QY,
                                              const float* __restrict__ QD,
                                              const float* __restrict__ WT,
                                              const float* __restrict__ g,
                                              const float* __restrict__ y0,
                                              const float* __restrict__ usY,
                                              const float* __restrict__ usD,
                                              float* __restrict__ vs,
                                              double spY, double spD,
                                              double m00, double m01,
                                              double m10, double m11,
                                              double b00, double b01,
                                              double b10, double b11) {
    const int b = blockIdx.x;                 // 100 = SC*4
    const int s = b >> 2;
    const int d = (b & 3) * 256 + threadIdx.x;
    float w[NB];
#pragma unroll
    for (int k = 0; k < NB; ++k) w[k] = WT[k * DIM + d];   // coalesced
    const float gd  = g[d];
    const float gd0 = gd - y0[d];
    double vy = (double)y0[d], vdy = 0.0;
    for (int i = 0; i < s; ++i) {             // superchunk prefix with B = M^SS
        double uy = (double)usY[i * DIM + d];
        double ud = (double)usD[i * DIM + d];
        double ny  = b00 * vy + b01 * vdy + uy;
        double ndy = b10 * vy + b11 * vdy + ud;
        vy = ny; vdy = ndy;
    }
    for (int i = 0; i < SS; ++i) {            // recover chunk starts with M
        int c = s * SS + i;
        vs[c * DIM + d] = (float)vy;
        vs[CHUNKS * DIM + c * DIM + d] = (float)vdy;
        float sy = 0.f, sd = 0.f;
#pragma unroll
        for (int k = 0; k < NB; ++k) {
            sy += w[k] * QY[c * QS + k];
            sd += w[k] * QD[c * QS + k];
        }
        double ry = (double)(float)((double)gd * spY + (double)gd0 * (double)sy);
        double rd = (double)(float)((double)gd * spD + (double)gd0 * (double)sd);
        double ny  = m00 * vy + m01 * vdy + ry;
        double ndy = m10 * vy + m11 * vdy + rd;
        vy = ny; vdy = ndy;
    }
}

// R10's best-measured roll, verbatim.
__global__ __launch_bounds__(256) void k_roll(const float* __restrict__ q,
                                              const float* __restrict__ WT,
                                              const float* __restrict__ g,
                                              const float* __restrict__ y0,
                                              const float* __restrict__ vs,
                                              float* __restrict__ out) {
    __shared__ float lq[LSTEPS][QS];                   // 5.12 KB
    const int c = blockIdx.y;
    const int tid = threadIdx.x;
    const int d = blockIdx.x * 256 + tid;
    {   // stage this chunk's q slice (320 float4)
        const float4* src = (const float4*)(q + (size_t)c * LSTEPS * QS);
        float4* dst = (float4*)&lq[0][0];
        for (int i = tid; i < LSTEPS * (QS / 4); i += 256) dst[i] = src[i];
    }
    float w[NB];
#pragma unroll
    for (int k = 0; k < NB; ++k) w[k] = WT[k * DIM + d];   // coalesced
    const float y0d = y0[d];
    const float gd  = g[d];
    const float gd0 = gd - y0d;
    float y  = vs[c * DIM + d];
    float dy = vs[CHUNKS * DIM + c * DIM + d];
    __syncthreads();
    if (c == 0) {                                      // row 0: [y0 | y0 | 0]
        out[d] = y0d;
        out[DIM + d] = y0d;
        out[2 * DIM + d] = 0.f;
    }
    float* op = out + (size_t)(c * LSTEPS + 1) * (3 * DIM);
#pragma unroll 2
    for (int j = 0; j < LSTEPS; ++j) {
        const float4* row = (const float4*)&lq[j][0];  // broadcast reads
        float dot = 0.f;
#pragma unroll
        for (int m = 0; m < 6; ++m) {
            float4 qv = row[m];
            dot += w[4 * m + 0] * qv.x;
            dot += w[4 * m + 1] * qv.y;
            dot += w[4 * m + 2] * qv.z;
            dot += w[4 * m + 3] * qv.w;
        }
        dot += w[24] * lq[j][24];
        float f   = dot * gd0;
        float ddy = 25.0f * (6.25f * (gd - y) - dy) + f;
        dy = dy + 0.001f * ddy;
        y  = y + 0.001f * dy;
        op[d] = y0d;
        op[DIM + d] = y;
        op[2 * DIM + d] = dy;
        op += 3 * DIM;
    }
}

extern "C" void kernel_launch(void* const* d_in, const int* in_sizes, int n_in,
                              void* d_out, int out_size, void* d_ws, size_t ws_size,
                              hipStream_t stream) {
    const float* y0 = (const float*)d_in[0];
    const float* g  = (const float*)d_in[1];
    const float* W  = (const float*)d_in[2];
    float* out = (float*)d_out;

    float* q   = (float*)d_ws;                        // [NSTEP][QS]      1.28 MB
    float* QY  = q   + (size_t)NSTEP * QS;            // [CHUNKS][QS]
    float* QD  = QY  + (size_t)CHUNKS * QS;
    float* WT  = QD  + (size_t)CHUNKS * QS;           // [NB][DIM]
    float* usY = WT  + (size_t)NB * DIM;              // [SC][DIM]
    float* usD = usY + (size_t)SC * DIM;
    float* vs  = usD + (size_t)SC * DIM;              // [2][CHUNKS][DIM] 2 MB

    // A (f64 with fp32-rounded dt), M = A^L, B = M^SS, sp = 156.25*sum A^i(dt^2,dt)
    const double dtD = (double)0.001f;
    const double aD = 25.0, abD = 25.0 * 6.25;
    const double a00 = 1.0 - dtD * dtD * abD;
    const double a01 = dtD * (1.0 - dtD * aD);
    const double a10 = -dtD * abD;
    const double a11 = 1.0 - dtD * aD;
    double m00 = 1, m01 = 0, m10 = 0, m11 = 1;
    double py = dtD * dtD, pd = dtD, sY = 0.0, sD = 0.0;
    for (int i = 0; i < LSTEPS; ++i) {
        double t00 = a00 * m00 + a01 * m10;
        double t01 = a00 * m01 + a01 * m11;
        double t10 = a10 * m00 + a11 * m10;
        double t11 = a10 * m01 + a11 * m11;
        m00 = t00; m01 = t01; m10 = t10; m11 = t11;
        sY += py; sD += pd;
        double npy = a00 * py + a01 * pd;
        double npd = a10 * py + a11 * pd;
        py = npy; pd = npd;
    }
    double b00 = 1, b01 = 0, b10 = 0, b11 = 1;        // B = M^SS
    for (int i = 0; i < SS; ++i) {
        double t00 = m00 * b00 + m01 * b10;
        double t01 = m00 * b01 + m01 * b11;
        double t10 = m10 * b00 + m11 * b10;
        double t11 = m10 * b01 + m11 * b11;
        b00 = t00; b01 = t01; b10 = t10; b11 = t11;
    }
    const double spY = 156.25 * sY;
    const double spD = 156.25 * sD;
    const double logdecay = log((double)(1.0f - 0.001f));

    k_prep<<<CHUNKS + NB, 64, 0, stream>>>(q, QY, QD, WT, W, logdecay, a00, a01, a10, a11);
    k_midA<<<SC * 4, 256, 0, stream>>>(QY, QD, WT, g, y0, usY, usD,
                                       spY, spD, m00, m01, m10, m11);
    k_midB<<<SC * 4, 256, 0, stream>>>(QY, QD, WT, g, y0, usY, usD, vs,
                                       spY, spD, m00, m01, m10, m11,
                                       b00, b01, b10, b11);
    k_roll<<<dim3(DIM / 256, CHUNKS), 256, 0, stream>>>(q, WT, g, y0, vs, out);
}